// Round 1
// baseline (515.080 us; speedup 1.0000x reference)
//
#include <hip/hip_runtime.h>
#include <stdint.h>

// ---------------------------------------------------------------------------
// Fused 2-layer tanh RNN + FC head for MI355X (gfx950).
//
// Shapes: x[512,1024,32] fp32, H1=128, H2=64, C=10.
// Strategy: 32 blocks x 256 threads (4 waves), 16 batch rows per block.
// The whole T=1024 time loop runs inside the block (serial recurrence).
// GEMMs are "swapped" MFMA fp16: D[ch][batch] = W[ch][k] * h^T[k][batch],
// so ALL weights live in registers as A-fragments for the entire kernel;
// activations are fp16 B-fragments in XOR-swizzled LDS, double-buffered.
// Layer 2 lags layer 1 by one step -> both phases read the same h1 buffer
// -> ONE __syncthreads() per timestep.
// ---------------------------------------------------------------------------

typedef _Float16 f16x8 __attribute__((ext_vector_type(8)));
typedef float f32x4 __attribute__((ext_vector_type(4)));

#define MFMA_F16(A, B, C) __builtin_amdgcn_mfma_f32_16x16x32_f16((A), (B), (C), 0, 0, 0)

__device__ __forceinline__ float tanh_fast(float x) {
  // tanh(x) = 1 - 2/(1 + 2^(x*2*log2 e)); exact at +-inf, abs err ~1e-6.
  float t = __builtin_amdgcn_exp2f(x * 2.88539008177792681472f);
  return 1.0f - 2.0f * __builtin_amdgcn_rcpf(t + 1.0f);
}

__device__ __forceinline__ uint32_t pk16(float a, float b) {
  return __builtin_bit_cast(uint32_t, __builtin_amdgcn_cvt_pkrtz(a, b));
}

__global__ __launch_bounds__(256) void rnn_fused(
    const float* __restrict__ x,
    const float* __restrict__ Wih1, const float* __restrict__ Whh1,
    const float* __restrict__ bih1, const float* __restrict__ bhh1,
    const float* __restrict__ Wih2, const float* __restrict__ Whh2,
    const float* __restrict__ bih2, const float* __restrict__ bhh2,
    const float* __restrict__ Wfc,  const float* __restrict__ bfc,
    float* __restrict__ out)
{
  constexpr int T = 1024, I = 32, H1 = 128, H2 = 64, BB = 16;

  // LDS map (bytes):
  //   H1[0] @ 0      (16 rows x 128 f16 = 4096B)   h1, double-buffered
  //   H1[1] @ 4096
  //   H2[0] @ 8192   (16 rows x  64 f16 = 2048B)   h2, double-buffered
  //   H2[1] @ 10240
  //   h2f   @ 12288  (16 rows x  64 f32 = 4096B)   final h2 for FC
  __shared__ __align__(16) unsigned char smem[16384];

  const int tid  = threadIdx.x;
  const int w    = tid >> 6;        // wave 0..3
  const int lane = tid & 63;
  const int g    = lane >> 4;       // k-group 0..3
  const int n    = lane & 15;       // batch col 0..15
  const int b0   = blockIdx.x * BB;

  // ---- zero h1(0), h2(0) ----
  {
    uint32_t* p = (uint32_t*)smem;
    for (int i = tid; i < 1024; i += 256) p[i] = 0u;          // H1[0]
    uint32_t* q = (uint32_t*)(smem + 8192);
    for (int i = tid; i < 512; i += 256) q[i] = 0u;           // H2[0]
  }

  // ---- weights -> register A-fragments (fp16), loaded once ----
  // A-frag layout for mfma_f32_16x16x32_f16: m = lane&15, k = (lane>>4)*8 + j.
  auto cvt8 = [](const float* s) -> f16x8 {
    f16x8 r;
#pragma unroll
    for (int j = 0; j < 8; ++j) r[j] = (_Float16)s[j];
    return r;
  };

  f16x8 aU[2][4];   // W_hh1 for this wave's 2 channel tiles (ch = 32w..32w+31)
  f16x8 aI1[2];     // W_ih1 (K=32 -> single k-step)
  f16x8 aI2[4];     // W_ih2 for this wave's l2 tile (ch2 = 16w..16w+15)
  f16x8 aR2[2];     // W_hh2
#pragma unroll
  for (int ti = 0; ti < 2; ++ti) {
    const int ch = (2 * w + ti) * 16 + n;
#pragma unroll
    for (int k4 = 0; k4 < 4; ++k4)
      aU[ti][k4] = cvt8(Whh1 + ch * H1 + k4 * 32 + g * 8);
    aI1[ti] = cvt8(Wih1 + ch * I + g * 8);
  }
  {
    const int ch2 = w * 16 + n;
#pragma unroll
    for (int k4 = 0; k4 < 4; ++k4)
      aI2[k4] = cvt8(Wih2 + ch2 * H1 + k4 * 32 + g * 8);
#pragma unroll
    for (int k2 = 0; k2 < 2; ++k2)
      aR2[k2] = cvt8(Whh2 + ch2 * H2 + k2 * 32 + g * 8);
  }

  // Biases folded into the MFMA C-init. D layout: col=lane&15, row=(lane>>4)*4+r.
  f32x4 bias1[2], bias2;
#pragma unroll
  for (int ti = 0; ti < 2; ++ti) {
    const int ch = (2 * w + ti) * 16 + g * 4;
#pragma unroll
    for (int r = 0; r < 4; ++r) bias1[ti][r] = bih1[ch + r] + bhh1[ch + r];
  }
  {
    const int ch2 = w * 16 + g * 4;
#pragma unroll
    for (int r = 0; r < 4; ++r) bias2[r] = bih2[ch2 + r] + bhh2[ch2 + r];
  }

  // ---- per-lane LDS byte offsets (constant across iterations) ----
  // Linear layout: row n (batch), channel ch -> byte n*rowB + ch*2.
  // Swizzle: 16B slot index ^= (n&7)  => uniform bank spread for b128/b64 ops.
  int roff1[4], roff2[2], woff1[2], woff2;
#pragma unroll
  for (int k4 = 0; k4 < 4; ++k4)
    roff1[k4] = n * 256 + (((k4 * 4 + g) ^ (n & 7)) << 4);
#pragma unroll
  for (int k2 = 0; k2 < 2; ++k2)
    roff2[k2] = n * 128 + (((k2 * 4 + g) ^ (n & 7)) << 4);
#pragma unroll
  for (int ti = 0; ti < 2; ++ti) {
    const int tt = 2 * w + ti;
    woff1[ti] = n * 256 + (((2 * tt + (g >> 1)) ^ (n & 7)) << 4) + (g & 1) * 8;
  }
  woff2 = n * 128 + (((2 * w + (g >> 1)) ^ (n & 7)) << 4) + (g & 1) * 8;

  // ---- x prefetch (distance 2): B-frag k=i=(lane>>4)*8+j, col=batch ----
  const float* xp = x + (size_t)(b0 + n) * T * I + g * 8;
  f32x4 xrA0 = *(const f32x4*)(xp + 0 * I);
  f32x4 xrA1 = *(const f32x4*)(xp + 0 * I + 4);
  f32x4 xrB0 = *(const f32x4*)(xp + 1 * I);
  f32x4 xrB1 = *(const f32x4*)(xp + 1 * I + 4);

  __syncthreads();

  auto tanh_pack = [&](const f32x4& a, uint32_t& lo, uint32_t& hi) {
    const float v0 = tanh_fast(a[0]), v1 = tanh_fast(a[1]);
    const float v2 = tanh_fast(a[2]), v3 = tanh_fast(a[3]);
    lo = pk16(v0, v1);
    hi = pk16(v2, v3);
  };

  // One fused timestep. cur is a compile-time 0/1 at each call site.
  auto step = [&](int t, int cur, f32x4& xr0, f32x4& xr1) {
    // convert this step's x to fp16 B-frag
    f16x8 xf;
    {
      union { uint32_t u[4]; f16x8 v; } tmp;
      tmp.u[0] = pk16(xr0[0], xr0[1]);
      tmp.u[1] = pk16(xr0[2], xr0[3]);
      tmp.u[2] = pk16(xr1[0], xr1[1]);
      tmp.u[3] = pk16(xr1[2], xr1[3]);
      xf = tmp.v;
    }

    const char* H1c = (const char*)smem + cur * 4096;         // h1(t)
    char*       H1n = (char*)smem + (cur ^ 1) * 4096;         // h1(t+1)
    const char* H2r = (const char*)smem + 8192 + (cur ^ 1) * 2048; // h2(t-1)
    char*       H2w = (char*)smem + 8192 + cur * 2048;        // h2(t)

    // h1(t) B-fragments -- shared by l1 recurrence AND l2 input projection
    f16x8 b1[4];
#pragma unroll
    for (int k4 = 0; k4 < 4; ++k4)
      b1[k4] = *(const f16x8*)(H1c + roff1[k4]);

    // ---- layer 1: h1(t+1) = tanh(Wih1 x(t) + Whh1 h1(t) + b) ----
    f32x4 acc0 = bias1[0];
    f32x4 acc1 = bias1[1];
    acc0 = MFMA_F16(aI1[0], xf, acc0);
    acc1 = MFMA_F16(aI1[1], xf, acc1);
#pragma unroll
    for (int k4 = 0; k4 < 4; ++k4) {
      acc0 = MFMA_F16(aU[0][k4], b1[k4], acc0);
      acc1 = MFMA_F16(aU[1][k4], b1[k4], acc1);
    }

    // issue x prefetch for t+2 (consumed two steps later)
    if (t + 2 < T) {
      xr0 = *(const f32x4*)(xp + (t + 2) * I);
      xr1 = *(const f32x4*)(xp + (t + 2) * I + 4);
    }

    // ---- layer 2 (lagged): h2(t) = tanh(Wih2 h1(t) + Whh2 h2(t-1) + b) ----
    if (t > 0) {
      f16x8 b2[2];
#pragma unroll
      for (int k2 = 0; k2 < 2; ++k2)
        b2[k2] = *(const f16x8*)(H2r + roff2[k2]);
      f32x4 acc2 = bias2;
#pragma unroll
      for (int k4 = 0; k4 < 4; ++k4) acc2 = MFMA_F16(aI2[k4], b1[k4], acc2);
#pragma unroll
      for (int k2 = 0; k2 < 2; ++k2) acc2 = MFMA_F16(aR2[k2], b2[k2], acc2);
      uint32_t lo, hi;
      tanh_pack(acc2, lo, hi);
      *(uint2*)(H2w + woff2) = make_uint2(lo, hi);
    }

    // layer-1 epilogue: tanh -> fp16 -> LDS (next buffer)
    {
      uint32_t lo, hi;
      tanh_pack(acc0, lo, hi);
      *(uint2*)(H1n + woff1[0]) = make_uint2(lo, hi);
      tanh_pack(acc1, lo, hi);
      *(uint2*)(H1n + woff1[1]) = make_uint2(lo, hi);
    }

    __syncthreads();  // the ONE barrier per timestep
  };

  for (int t2 = 0; t2 < T; t2 += 2) {
    step(t2,     0, xrA0, xrA1);
    step(t2 + 1, 1, xrB0, xrB1);
  }

  // ---- final l2 step: h2(T) = tanh(Wih2 h1(T) + Whh2 h2(T-1) + b) ----
  // After the loop: h1(T) is in H1[0], h2(T-1) is in H2[1].
  {
    const char* H1c = (const char*)smem;                 // h1(T)
    const char* H2r = (const char*)smem + 8192 + 2048;   // h2(T-1)
    f16x8 b1[4];
#pragma unroll
    for (int k4 = 0; k4 < 4; ++k4)
      b1[k4] = *(const f16x8*)(H1c + roff1[k4]);
    f16x8 b2[2];
#pragma unroll
    for (int k2 = 0; k2 < 2; ++k2)
      b2[k2] = *(const f16x8*)(H2r + roff2[k2]);
    f32x4 acc2 = bias2;
#pragma unroll
    for (int k4 = 0; k4 < 4; ++k4) acc2 = MFMA_F16(aI2[k4], b1[k4], acc2);
#pragma unroll
    for (int k2 = 0; k2 < 2; ++k2) acc2 = MFMA_F16(aR2[k2], b2[k2], acc2);

    f32x4 hv;
#pragma unroll
    for (int r = 0; r < 4; ++r) hv[r] = tanh_fast(acc2[r]);
    const int ch0 = w * 16 + g * 4;  // D layout: row = ch-in-tile, col = batch n
    *(f32x4*)(smem + 12288 + n * 256 + ch0 * 4) = hv;
  }
  __syncthreads();

  // ---- FC head: logits[b][c] = b_fc[c] + sum_k h2f[b][k] * Wfc[c][k] ----
  if (tid < BB * 10) {
    const int b = tid / 10, c = tid % 10;
    const float* hrow = (const float*)(smem + 12288 + b * 256);
    float acc = bfc[c];
#pragma unroll 8
    for (int k = 0; k < 64; ++k) acc += hrow[k] * Wfc[c * 64 + k];
    out[(size_t)(b0 + b) * 10 + c] = acc;
  }
}

extern "C" void kernel_launch(void* const* d_in, const int* in_sizes, int n_in,
                              void* d_out, int out_size, void* d_ws, size_t ws_size,
                              hipStream_t stream) {
  const float* x    = (const float*)d_in[0];
  const float* Wih1 = (const float*)d_in[1];
  const float* Whh1 = (const float*)d_in[2];
  const float* bih1 = (const float*)d_in[3];
  const float* bhh1 = (const float*)d_in[4];
  const float* Wih2 = (const float*)d_in[5];
  const float* Whh2 = (const float*)d_in[6];
  const float* bih2 = (const float*)d_in[7];
  const float* bhh2 = (const float*)d_in[8];
  const float* Wfc  = (const float*)d_in[9];
  const float* bfc  = (const float*)d_in[10];

  hipLaunchKernelGGL(rnn_fused, dim3(512 / 16), dim3(256), 0, stream,
                     x, Wih1, Whh1, bih1, bhh1, Wih2, Whh2, bih2, bhh2,
                     Wfc, bfc, (float*)d_out);
}